// Round 4
// baseline (414.685 us; speedup 1.0000x reference)
//
#include <hip/hip_runtime.h>
#include <stdint.h>

// Problem constants (fixed by the reference): B=8, H=W=64, C=256
#define CC 256
#define NN 4096           // H*W
#define MM 2048           // NN/2 (pooled)
#define BB 8
#define NROWS (BB*NN)     // 32768 query rows
#define PROWS (BB*MM)     // 16384 pooled rows

typedef __attribute__((ext_vector_type(8))) short    short8;   // 8 bf16
typedef __attribute__((ext_vector_type(8))) _Float16 half8;    // 8 fp16
typedef __attribute__((ext_vector_type(4))) float    float4v;

__device__ __forceinline__ unsigned short f2bf(float f) {
    unsigned int u = __float_as_uint(f);
    u += 0x7fffu + ((u >> 16) & 1u);
    return (unsigned short)(u >> 16);
}
__device__ __forceinline__ float bf2f(unsigned short h) {
    return __uint_as_float(((unsigned int)h) << 16);
}
__device__ __forceinline__ unsigned short f2h(float f) {
    union { _Float16 h; unsigned short u; } cv; cv.h = (_Float16)f; return cv.u;
}
__device__ __forceinline__ float h2f(unsigned short u) {
    union { _Float16 h; unsigned short u; } cv; cv.u = u; return (float)cv.h;
}

// ---------------------------------------------------------------------------
// wsplit: transpose + bf16 hi/lo split the three 256x256 weights once.
// wT_hi/wT_lo layout: [widx][outcol][k]  (MFMA B-frags 16B contiguous)
// ---------------------------------------------------------------------------
__global__ void wsplit_kernel(const float* __restrict__ w_theta,
                              const float* __restrict__ w_phi,
                              const float* __restrict__ w_g,
                              unsigned short* __restrict__ wT_hi,
                              unsigned short* __restrict__ wT_lo)
{
    __shared__ float tile[64][65];
    const int widx = blockIdx.z;
    const int kt = blockIdx.x, ct = blockIdx.y;
    const float* w = (widx == 0) ? w_theta : (widx == 1) ? w_phi : w_g;
    const int t  = threadIdx.x;
    const int tc = t & 63, tr = t >> 6;
    #pragma unroll
    for (int i = 0; i < 16; ++i) {
        const int lk = tr*16 + i;
        tile[lk][tc] = w[(size_t)(kt*64 + lk)*CC + ct*64 + tc];
    }
    __syncthreads();
    #pragma unroll
    for (int i = 0; i < 16; ++i) {
        const int lc = tr*16 + i;
        float v = tile[tc][lc];
        const int c = ct*64 + lc, k = kt*64 + tc;
        unsigned short hh = f2bf(v);
        size_t o = ((size_t)widx*CC + c)*CC + k;
        wT_hi[o] = hh;
        wT_lo[o] = f2bf(v - bf2f(hh));
    }
}

// ---------------------------------------------------------------------------
// proj_kernel v4: one 64-row x 64-col slice of ONE projection per block
// (low register pressure: acc[4] = 16 VGPRs, no spills). W pre-split ->
// staging is pure uint4 copies. x split to bf16 hi/lo in-register per K-step.
// Flat grid 6144, id = cv*512 + rb: all 12 col-variants of row-block rb land
// on XCD rb%8 (id%8 heuristic) -> x re-reads are XCD-L2-local, not L3.
// Outputs: theta -> fp16 hi/lo unpooled; phi -> maxpool fp16;
//          g -> maxpool bf16 transposed g_t[b][c][m].
// ---------------------------------------------------------------------------
__global__ __launch_bounds__(256, 4) void proj_kernel(
    const float* __restrict__ x,
    const unsigned short* __restrict__ wT_hi,
    const unsigned short* __restrict__ wT_lo,
    unsigned short* __restrict__ th_hi,
    unsigned short* __restrict__ th_lo,
    unsigned short* __restrict__ ph,
    unsigned short* __restrict__ g_t)
{
    __shared__ unsigned short wt_hi[64*136];   // [64 cols][128 k + pad]
    __shared__ unsigned short wt_lo[64*136];

    const int tid  = threadIdx.x;
    const int rb   = blockIdx.x & 511;         // row-block (XCD = rb%8)
    const int cv   = blockIdx.x >> 9;          // 0..11 col-variant
    const int r0   = rb * 64;
    const int widx = cv >> 2;
    const int wc0  = (cv & 3) * 64;
    const unsigned short* wThp = wT_hi + ((size_t)widx*CC + wc0)*CC;
    const unsigned short* wTlp = wT_lo + ((size_t)widx*CC + wc0)*CC;

    const int wv   = tid >> 6;
    const int lane = tid & 63;
    const int quad = lane >> 4;
    const int l15  = lane & 15;
    const int arow = r0 + wv*16 + l15;

    float4v acc[4];
    #pragma unroll
    for (int nf = 0; nf < 4; ++nf) acc[nf] = (float4v){0.f,0.f,0.f,0.f};

    for (int h = 0; h < 2; ++h) {
        __syncthreads();
        {   // stage pre-split W^T tile [64 cols][128 k] (pure copy)
            const int j    = tid & 63;
            const int kseg = tid >> 6;
            const size_t base = (size_t)j*CC + h*128 + kseg*32;
            const unsigned short* sh = wThp + base;
            const unsigned short* sl = wTlp + base;
            unsigned short* dh = &wt_hi[j*136 + kseg*32];
            unsigned short* dl = &wt_lo[j*136 + kseg*32];
            #pragma unroll
            for (int u = 0; u < 4; ++u) {
                *(uint4*)(dh + u*8) = *(const uint4*)(sh + u*8);
                *(uint4*)(dl + u*8) = *(const uint4*)(sl + u*8);
            }
        }
        __syncthreads();

        #pragma unroll
        for (int ks = 0; ks < 4; ++ks) {
            const float* ap = x + (size_t)arow*CC + h*128 + ks*32 + quad*8;
            float4v a0 = *(const float4v*)ap;
            float4v a1 = *(const float4v*)(ap + 4);
            short8 a_hi, a_lo;
            #pragma unroll
            for (int jj = 0; jj < 4; ++jj) {
                unsigned short h0 = f2bf(a0[jj]);
                a_hi[jj]   = (short)h0; a_lo[jj]   = (short)f2bf(a0[jj] - bf2f(h0));
                unsigned short h1 = f2bf(a1[jj]);
                a_hi[4+jj] = (short)h1; a_lo[4+jj] = (short)f2bf(a1[jj] - bf2f(h1));
            }
            #pragma unroll
            for (int nf = 0; nf < 4; ++nf) {
                const int wrow = nf*16 + l15;
                short8 b_hi = *(const short8*)&wt_hi[wrow*136 + ks*32 + quad*8];
                short8 b_lo = *(const short8*)&wt_lo[wrow*136 + ks*32 + quad*8];
                acc[nf] = __builtin_amdgcn_mfma_f32_16x16x32_bf16(a_hi, b_hi, acc[nf], 0,0,0);
                acc[nf] = __builtin_amdgcn_mfma_f32_16x16x32_bf16(a_hi, b_lo, acc[nf], 0,0,0);
                acc[nf] = __builtin_amdgcn_mfma_f32_16x16x32_bf16(a_lo, b_hi, acc[nf], 0,0,0);
            }
        }
    }

    const int rowbase = r0 + wv*16 + quad*4;
    if (widx == 0) {                           // theta: unpooled, fp16 hi/lo
        #pragma unroll
        for (int nf = 0; nf < 4; ++nf) {
            const int c = wc0 + nf*16 + l15;
            #pragma unroll
            for (int r = 0; r < 4; ++r) {
                float v = acc[nf][r];
                unsigned short hh = f2h(v);
                size_t idx = (size_t)(rowbase + r)*CC + c;
                th_hi[idx] = hh;
                th_lo[idx] = f2h(v - h2f(hh));
            }
        }
    } else if (widx == 1) {                    // phi: pool row pairs, fp16
        #pragma unroll
        for (int nf = 0; nf < 4; ++nf) {
            const int c = wc0 + nf*16 + l15;
            #pragma unroll
            for (int rp = 0; rp < 2; ++rp) {
                float v = fmaxf(acc[nf][2*rp], acc[nf][2*rp+1]);
                const int prow = rowbase/2 + rp;   // rowbase even -> exact
                ph[(size_t)prow*CC + c] = f2h(v);
            }
        }
    } else {                                   // g: pool, bf16, transposed
        #pragma unroll
        for (int nf = 0; nf < 4; ++nf) {
            const int c = wc0 + nf*16 + l15;
            #pragma unroll
            for (int rp = 0; rp < 2; ++rp) {
                float v = fmaxf(acc[nf][2*rp], acc[nf][2*rp+1]);
                const int prow = rowbase/2 + rp;
                const int b = prow >> 11;
                const int m = prow & 2047;
                g_t[((size_t)b*CC + c)*MM + m] = f2bf(v);
            }
        }
    }
}

// ---------------------------------------------------------------------------
// phimean: per-batch column mean of phi (fp32), for the per-row softmax shift.
// ---------------------------------------------------------------------------
__global__ void phimean_kernel(const unsigned short* __restrict__ ph,
                               float* __restrict__ phbar)
{
    const int b = blockIdx.x >> 3, chunk = blockIdx.x & 7;
    const int c = threadIdx.x;
    const size_t base = ((size_t)b*MM + chunk*256)*CC + c;
    float s = 0.f;
    for (int r = 0; r < 256; ++r) s += h2f(ph[base + (size_t)r*CC]);
    atomicAdd(&phbar[b*CC + c], s * (1.0f/MM));
}

// ---------------------------------------------------------------------------
// attn_kernel v4: shift softmax, per-row shift = theta.phibar + 128, exp-arg
// clamped to [-85,85] (NaN impossible). fp16 2-pass S; bf16 PV; ones-MFMA l.
// (256,3): 3 blocks/CU (LDS 42.5KB*3 = 127.5KB, VGPR 100 <= 170).
// ---------------------------------------------------------------------------
__global__ __launch_bounds__(256, 3) void attn_kernel(
    const float* __restrict__ x,
    const unsigned short* __restrict__ th_hi,
    const unsigned short* __restrict__ th_lo,
    const unsigned short* __restrict__ ph,
    const unsigned short* __restrict__ g_t,
    const float* __restrict__ phbar,
    float* __restrict__ out)
{
    __shared__ unsigned short s_ph[32*264];    // phi tile fp16, padded rows
    __shared__ unsigned short s_gt[256*40];    // g tile bf16, transposed, padded
    __shared__ unsigned short s_p[4][16*40];   // per-wave P scratch (bf16)

    const int tid  = threadIdx.x;
    const int q0   = blockIdx.x * 64;
    const int b    = q0 >> 12;
    const int wv   = tid >> 6;
    const int lane = tid & 63;
    const int quad = lane >> 4;
    const int l15  = lane & 15;

    // theta A-frags (fp16 hi/lo) for this wave's 16 rows
    half8 t_hi[8], t_lo[8];
    {
        const unsigned short* bh = th_hi + (size_t)(q0 + wv*16 + l15)*CC;
        const unsigned short* bl = th_lo + (size_t)(q0 + wv*16 + l15)*CC;
        #pragma unroll
        for (int ks = 0; ks < 8; ++ks) {
            t_hi[ks] = *(const half8*)(bh + ks*32 + quad*8);
            t_lo[ks] = *(const half8*)(bl + ks*32 + quad*8);
        }
    }

    // per-row shift = theta . phibar (+128), moved to C-layout rows via shfl
    float sh128[4];
    {
        float sp = 0.f;
        #pragma unroll
        for (int ks = 0; ks < 8; ++ks) {
            const int k0 = ks*32 + quad*8;
            float4v m0 = *(const float4v*)&phbar[b*CC + k0];
            float4v m1 = *(const float4v*)&phbar[b*CC + k0 + 4];
            #pragma unroll
            for (int j = 0; j < 4; ++j) {
                sp += (float)t_hi[ks][j]   * m0[j];
                sp += (float)t_hi[ks][4+j] * m1[j];
            }
        }
        sp += __shfl_xor(sp, 16);
        sp += __shfl_xor(sp, 32);
        #pragma unroll
        for (int r = 0; r < 4; ++r)
            sh128[r] = __shfl(sp, quad*4 + r) + 128.f;
    }

    float4v O[16];
    #pragma unroll
    for (int ct = 0; ct < 16; ++ct) O[ct] = (float4v){0.f,0.f,0.f,0.f};
    float4v accl = (float4v){0.f,0.f,0.f,0.f};

    short8 ones;
    #pragma unroll
    for (int j = 0; j < 8; ++j) ones[j] = (short)0x3F80;   // bf16 1.0

    const size_t phbase = (size_t)b * MM * CC;
    const size_t gtbase = (size_t)b * CC * MM;

    for (int kt = 0; kt < 64; ++kt) {
        const int key0 = kt * 32;
        __syncthreads();
        {   // stage phi [32][256] fp16 and g_t [256][32] bf16
            const int i  = tid >> 3;
            const int cs = (tid & 7) * 32;
            const unsigned short* sh = ph + phbase + (size_t)(key0 + i)*CC + cs;
            unsigned short* dh = &s_ph[i*264 + cs];
            #pragma unroll
            for (int u = 0; u < 4; ++u)
                *(uint4*)(dh + u*8) = *(const uint4*)(sh + u*8);
            const unsigned short* sg = g_t + gtbase + (size_t)tid*MM + key0;
            unsigned short* dg = &s_gt[tid*40];
            #pragma unroll
            for (int u = 0; u < 4; ++u)
                *(uint4*)(dg + u*8) = *(const uint4*)(sg + u*8);
        }
        __syncthreads();

        // S = theta @ phi^T, fp16 2-pass (hi + lo)
        float4v S0 = (float4v){0.f,0.f,0.f,0.f};
        float4v S1 = (float4v){0.f,0.f,0.f,0.f};
        #pragma unroll
        for (int ks = 0; ks < 8; ++ks) {
            half8 b0 = *(const half8*)&s_ph[( 0 + l15)*264 + ks*32 + quad*8];
            half8 b1 = *(const half8*)&s_ph[(16 + l15)*264 + ks*32 + quad*8];
            S0 = __builtin_amdgcn_mfma_f32_16x16x32_f16(t_hi[ks], b0, S0, 0,0,0);
            S1 = __builtin_amdgcn_mfma_f32_16x16x32_f16(t_hi[ks], b1, S1, 0,0,0);
            S0 = __builtin_amdgcn_mfma_f32_16x16x32_f16(t_lo[ks], b0, S0, 0,0,0);
            S1 = __builtin_amdgcn_mfma_f32_16x16x32_f16(t_lo[ks], b1, S1, 0,0,0);
        }

        // p = exp(clamp(S - shift, -85, 85)) -> bf16 (no row reductions)
        unsigned short* pw = &s_p[wv][0];
        #pragma unroll
        for (int r = 0; r < 4; ++r) {
            float a0 = fminf(fmaxf(S0[r] - sh128[r], -85.f), 85.f);
            float a1 = fminf(fmaxf(S1[r] - sh128[r], -85.f), 85.f);
            pw[(quad*4 + r)*40 + l15]      = f2bf(__expf(a0));
            pw[(quad*4 + r)*40 + 16 + l15] = f2bf(__expf(a1));
        }
        asm volatile("s_waitcnt lgkmcnt(0)" ::: "memory");
        short8 pfrag = *(const short8*)&s_p[wv][l15*40 + quad*8];

        // row-sum l via ones-column MFMA; O += P @ g
        accl = __builtin_amdgcn_mfma_f32_16x16x32_bf16(pfrag, ones, accl, 0,0,0);
        #pragma unroll
        for (int ct = 0; ct < 16; ++ct) {
            short8 gf = *(const short8*)&s_gt[(ct*16 + l15)*40 + quad*8];
            O[ct] = __builtin_amdgcn_mfma_f32_16x16x32_bf16(pfrag, gf, O[ct], 0,0,0);
        }
    }

    // epilogue: y = O/l, out = x + y
    float rl[4];
    #pragma unroll
    for (int r = 0; r < 4; ++r) rl[r] = 1.0f / accl[r];
    const int rowbase = q0 + wv*16 + quad*4;
    #pragma unroll
    for (int ct = 0; ct < 16; ++ct) {
        const int c = ct*16 + l15;
        #pragma unroll
        for (int r = 0; r < 4; ++r) {
            const size_t idx = (size_t)(rowbase + r)*CC + c;
            out[idx] = x[idx] + O[ct][r] * rl[r];
        }
    }
}

// ---------------------------------------------------------------------------
extern "C" void kernel_launch(void* const* d_in, const int* in_sizes, int n_in,
                              void* d_out, int out_size, void* d_ws, size_t ws_size,
                              hipStream_t stream) {
    const float* x       = (const float*)d_in[0];
    const float* w_theta = (const float*)d_in[1];
    const float* w_phi   = (const float*)d_in[2];
    const float* w_g     = (const float*)d_in[3];
    float* out = (float*)d_out;

    // workspace (~51.1 MB; verified ws >= 56 MB in round 1)
    unsigned short* th_hi = (unsigned short*)d_ws;                 // fp16 16.78 MB
    unsigned short* th_lo = th_hi + (size_t)NROWS*CC;              // fp16 16.78 MB
    unsigned short* ph    = th_lo + (size_t)NROWS*CC;              // fp16  8.39 MB
    unsigned short* g_t   = ph    + (size_t)PROWS*CC;              // bf16  8.39 MB
    unsigned short* wT_hi = g_t   + (size_t)PROWS*CC;              // bf16  0.39 MB
    unsigned short* wT_lo = wT_hi + (size_t)3*CC*CC;               // bf16  0.39 MB
    float*          phbar = (float*)(wT_lo + (size_t)3*CC*CC);     // fp32  8 KB

    hipMemsetAsync(phbar, 0, BB*CC*sizeof(float), stream);
    wsplit_kernel<<<dim3(4,4,3), 256, 0, stream>>>(w_theta, w_phi, w_g, wT_hi, wT_lo);
    proj_kernel<<<6144, 256, 0, stream>>>(x, wT_hi, wT_lo, th_hi, th_lo, ph, g_t);
    phimean_kernel<<<64, 256, 0, stream>>>(ph, phbar);
    attn_kernel<<<NROWS/64, 256, 0, stream>>>(x, th_hi, th_lo, ph, g_t, phbar, out);
}

// Round 5
// 313.807 us; speedup vs baseline: 1.3215x; 1.3215x over previous
//
#include <hip/hip_runtime.h>
#include <stdint.h>

// Problem constants (fixed by the reference): B=8, H=W=64, C=256
#define CC 256
#define NN 4096           // H*W
#define MM 2048           // NN/2 (pooled)
#define BB 8
#define NROWS (BB*NN)     // 32768 query rows
#define PROWS (BB*MM)     // 16384 pooled rows

typedef __attribute__((ext_vector_type(8))) short    short8;   // 8 bf16
typedef __attribute__((ext_vector_type(8))) _Float16 half8;    // 8 fp16
typedef __attribute__((ext_vector_type(4))) float    float4v;

__device__ __forceinline__ unsigned short f2bf(float f) {
    unsigned int u = __float_as_uint(f);
    u += 0x7fffu + ((u >> 16) & 1u);
    return (unsigned short)(u >> 16);
}
__device__ __forceinline__ float bf2f(unsigned short h) {
    return __uint_as_float(((unsigned int)h) << 16);
}
__device__ __forceinline__ unsigned short f2h(float f) {
    union { _Float16 h; unsigned short u; } cv; cv.h = (_Float16)f; return cv.u;
}
__device__ __forceinline__ float h2f(unsigned short u) {
    union { _Float16 h; unsigned short u; } cv; cv.u = u; return (float)cv.h;
}

// ---------------------------------------------------------------------------
// wsplit: transpose + bf16 hi/lo split the three 256x256 weights once.
// wT_hi/wT_lo layout: [widx][outcol][k]  (MFMA B-frags 16B contiguous)
// ---------------------------------------------------------------------------
__global__ void wsplit_kernel(const float* __restrict__ w_theta,
                              const float* __restrict__ w_phi,
                              const float* __restrict__ w_g,
                              unsigned short* __restrict__ wT_hi,
                              unsigned short* __restrict__ wT_lo)
{
    __shared__ float tile[64][65];
    const int widx = blockIdx.z;
    const int kt = blockIdx.x, ct = blockIdx.y;
    const float* w = (widx == 0) ? w_theta : (widx == 1) ? w_phi : w_g;
    const int t  = threadIdx.x;
    const int tc = t & 63, tr = t >> 6;
    #pragma unroll
    for (int i = 0; i < 16; ++i) {
        const int lk = tr*16 + i;
        tile[lk][tc] = w[(size_t)(kt*64 + lk)*CC + ct*64 + tc];
    }
    __syncthreads();
    #pragma unroll
    for (int i = 0; i < 16; ++i) {
        const int lc = tr*16 + i;
        float v = tile[tc][lc];
        const int c = ct*64 + lc, k = kt*64 + tc;
        unsigned short hh = f2bf(v);
        size_t o = ((size_t)widx*CC + c)*CC + k;
        wT_hi[o] = hh;
        wT_lo[o] = f2bf(v - bf2f(hh));
    }
}

// ---------------------------------------------------------------------------
// proj_kernel v5: one 64x64 slice of ONE projection per block (low pressure).
// theta/phi: 3-pass split-bf16 (feeds softmax logits -> needs ~2^-17 rel).
// g: 1-pass bf16 (stored bf16 anyway; error negligible in y).
// Outputs: theta -> fp16 single unpooled; phi -> maxpool fp16;
//          g -> maxpool bf16 transposed g_t[b][c][m].
// ---------------------------------------------------------------------------
__global__ __launch_bounds__(256, 4) void proj_kernel(
    const float* __restrict__ x,
    const unsigned short* __restrict__ wT_hi,
    const unsigned short* __restrict__ wT_lo,
    unsigned short* __restrict__ th,
    unsigned short* __restrict__ ph,
    unsigned short* __restrict__ g_t)
{
    __shared__ unsigned short wt_hi[64*136];   // [64 cols][128 k + pad]
    __shared__ unsigned short wt_lo[64*136];

    const int tid  = threadIdx.x;
    const int rb   = blockIdx.x & 511;         // row-block (XCD = rb%8)
    const int cv   = blockIdx.x >> 9;          // 0..11 col-variant
    const int r0   = rb * 64;
    const int widx = cv >> 2;
    const int wc0  = (cv & 3) * 64;
    const unsigned short* wThp = wT_hi + ((size_t)widx*CC + wc0)*CC;
    const unsigned short* wTlp = wT_lo + ((size_t)widx*CC + wc0)*CC;
    const bool split3 = (widx < 2);            // theta/phi 3-pass; g 1-pass

    const int wv   = tid >> 6;
    const int lane = tid & 63;
    const int quad = lane >> 4;
    const int l15  = lane & 15;
    const int arow = r0 + wv*16 + l15;

    float4v acc[4];
    #pragma unroll
    for (int nf = 0; nf < 4; ++nf) acc[nf] = (float4v){0.f,0.f,0.f,0.f};

    for (int h = 0; h < 2; ++h) {
        __syncthreads();
        {   // stage pre-split W^T tile [64 cols][128 k] (pure copy)
            const int j    = tid & 63;
            const int kseg = tid >> 6;
            const size_t base = (size_t)j*CC + h*128 + kseg*32;
            const unsigned short* sh = wThp + base;
            unsigned short* dh = &wt_hi[j*136 + kseg*32];
            #pragma unroll
            for (int u = 0; u < 4; ++u)
                *(uint4*)(dh + u*8) = *(const uint4*)(sh + u*8);
            if (split3) {
                const unsigned short* sl = wTlp + base;
                unsigned short* dl = &wt_lo[j*136 + kseg*32];
                #pragma unroll
                for (int u = 0; u < 4; ++u)
                    *(uint4*)(dl + u*8) = *(const uint4*)(sl + u*8);
            }
        }
        __syncthreads();

        #pragma unroll
        for (int ks = 0; ks < 4; ++ks) {
            const float* ap = x + (size_t)arow*CC + h*128 + ks*32 + quad*8;
            float4v a0 = *(const float4v*)ap;
            float4v a1 = *(const float4v*)(ap + 4);
            short8 a_hi, a_lo;
            #pragma unroll
            for (int jj = 0; jj < 4; ++jj) {
                unsigned short h0 = f2bf(a0[jj]);
                a_hi[jj]   = (short)h0; a_lo[jj]   = (short)f2bf(a0[jj] - bf2f(h0));
                unsigned short h1 = f2bf(a1[jj]);
                a_hi[4+jj] = (short)h1; a_lo[4+jj] = (short)f2bf(a1[jj] - bf2f(h1));
            }
            #pragma unroll
            for (int nf = 0; nf < 4; ++nf) {
                const int wrow = nf*16 + l15;
                short8 b_hi = *(const short8*)&wt_hi[wrow*136 + ks*32 + quad*8];
                acc[nf] = __builtin_amdgcn_mfma_f32_16x16x32_bf16(a_hi, b_hi, acc[nf], 0,0,0);
                if (split3) {
                    short8 b_lo = *(const short8*)&wt_lo[wrow*136 + ks*32 + quad*8];
                    acc[nf] = __builtin_amdgcn_mfma_f32_16x16x32_bf16(a_hi, b_lo, acc[nf], 0,0,0);
                    acc[nf] = __builtin_amdgcn_mfma_f32_16x16x32_bf16(a_lo, b_hi, acc[nf], 0,0,0);
                }
            }
        }
    }

    const int rowbase = r0 + wv*16 + quad*4;
    if (widx == 0) {                           // theta: unpooled, fp16 single
        #pragma unroll
        for (int nf = 0; nf < 4; ++nf) {
            const int c = wc0 + nf*16 + l15;
            #pragma unroll
            for (int r = 0; r < 4; ++r)
                th[(size_t)(rowbase + r)*CC + c] = f2h(acc[nf][r]);
        }
    } else if (widx == 1) {                    // phi: pool row pairs, fp16
        #pragma unroll
        for (int nf = 0; nf < 4; ++nf) {
            const int c = wc0 + nf*16 + l15;
            #pragma unroll
            for (int rp = 0; rp < 2; ++rp) {
                float v = fmaxf(acc[nf][2*rp], acc[nf][2*rp+1]);
                const int prow = rowbase/2 + rp;   // rowbase even -> exact
                ph[(size_t)prow*CC + c] = f2h(v);
            }
        }
    } else {                                   // g: pool, bf16, transposed
        #pragma unroll
        for (int nf = 0; nf < 4; ++nf) {
            const int c = wc0 + nf*16 + l15;
            #pragma unroll
            for (int rp = 0; rp < 2; ++rp) {
                float v = fmaxf(acc[nf][2*rp], acc[nf][2*rp+1]);
                const int prow = rowbase/2 + rp;
                const int b = prow >> 11;
                const int m = prow & 2047;
                g_t[((size_t)b*CC + c)*MM + m] = f2bf(v);
            }
        }
    }
}

// ---------------------------------------------------------------------------
// phimean v2: per-batch column mean of phi; 512 blocks (32 rows each).
// ---------------------------------------------------------------------------
__global__ void phimean_kernel(const unsigned short* __restrict__ ph,
                               float* __restrict__ phbar)
{
    const int b = blockIdx.x >> 6, chunk = blockIdx.x & 63;
    const int c = threadIdx.x;
    const size_t base = ((size_t)b*MM + chunk*32)*CC + c;
    float s = 0.f;
    for (int r = 0; r < 32; ++r) s += h2f(ph[base + (size_t)r*CC]);
    atomicAdd(&phbar[b*CC + c], s * (1.0f/MM));
}

// ---------------------------------------------------------------------------
// attn_kernel v5:
//  - 1-pass fp16 S (theta fp16 regs x phi fp16 LDS): 16 MFMA/tile/wave.
//  - shift softmax (per-row shift = theta.phibar + 128, clamp [-85,85]):
//    no reductions, NaN-impossible.
//  - PV col-split: wave w owns O[64 q][cols 64w..64w+63]; P shared via s_p
//    (block barrier); g B-frags DIRECT FROM GLOBAL (L2-resident) -> no s_gt,
//    LDS 42.5->22 KB, stride-20 conflict sources gone.
//  - row-sum l via ones-MFMA, broadcast through s_l at the end.
// ---------------------------------------------------------------------------
__global__ __launch_bounds__(256, 3) void attn_kernel(
    const float* __restrict__ x,
    const unsigned short* __restrict__ th,
    const unsigned short* __restrict__ ph,
    const unsigned short* __restrict__ g_t,
    const float* __restrict__ phbar,
    float* __restrict__ out)
{
    __shared__ unsigned short s_ph[32*264];    // phi tile fp16, padded rows
    __shared__ unsigned short s_p[4][16*40];   // P: [src wave][16 q][32 k pad 40]
    __shared__ float          s_l[64];         // final row sums

    const int tid  = threadIdx.x;
    const int q0   = blockIdx.x * 64;
    const int b    = q0 >> 12;
    const int wv   = tid >> 6;
    const int lane = tid & 63;
    const int quad = lane >> 4;
    const int l15  = lane & 15;

    // theta A-frags (fp16, single) for this wave's 16 rows
    half8 t_hi[8];
    {
        const unsigned short* bh = th + (size_t)(q0 + wv*16 + l15)*CC;
        #pragma unroll
        for (int ks = 0; ks < 8; ++ks)
            t_hi[ks] = *(const half8*)(bh + ks*32 + quad*8);
    }

    // per-row shift = theta . phibar (+128), moved to C-layout rows via shfl
    float sh128[4];
    {
        float sp = 0.f;
        #pragma unroll
        for (int ks = 0; ks < 8; ++ks) {
            const int k0 = ks*32 + quad*8;
            float4v m0 = *(const float4v*)&phbar[b*CC + k0];
            float4v m1 = *(const float4v*)&phbar[b*CC + k0 + 4];
            #pragma unroll
            for (int j = 0; j < 4; ++j) {
                sp += (float)t_hi[ks][j]   * m0[j];
                sp += (float)t_hi[ks][4+j] * m1[j];
            }
        }
        sp += __shfl_xor(sp, 16);
        sp += __shfl_xor(sp, 32);
        #pragma unroll
        for (int r = 0; r < 4; ++r)
            sh128[r] = __shfl(sp, quad*4 + r) + 128.f;
    }

    // O: all 64 block-queries x this wave's 64-col strip
    float4v O[4][4];                           // [row-tile][col-subtile]
    #pragma unroll
    for (int rt = 0; rt < 4; ++rt)
        #pragma unroll
        for (int ct = 0; ct < 4; ++ct) O[rt][ct] = (float4v){0.f,0.f,0.f,0.f};
    float4v accl = (float4v){0.f,0.f,0.f,0.f};

    short8 ones;
    #pragma unroll
    for (int j = 0; j < 8; ++j) ones[j] = (short)0x3F80;   // bf16 1.0

    const size_t phbase = (size_t)b * MM * CC;
    // this wave's g strip base: cols wv*64.., lane row l15, k-offset quad*8
    const unsigned short* gl =
        g_t + ((size_t)b*CC + wv*64 + l15)*MM + quad*8;

    for (int kt = 0; kt < 64; ++kt) {
        const int key0 = kt * 32;
        __syncthreads();                       // prev tile's s_ph/s_p reads done
        {   // stage phi [32 keys][256 c] fp16
            const int i  = tid >> 3;
            const int cs = (tid & 7) * 32;
            const unsigned short* sh = ph + phbase + (size_t)(key0 + i)*CC + cs;
            unsigned short* dh = &s_ph[i*264 + cs];
            #pragma unroll
            for (int u = 0; u < 4; ++u)
                *(uint4*)(dh + u*8) = *(const uint4*)(sh + u*8);
        }
        __syncthreads();

        // S = theta @ phi^T, 1-pass fp16
        float4v S0 = (float4v){0.f,0.f,0.f,0.f};
        float4v S1 = (float4v){0.f,0.f,0.f,0.f};
        #pragma unroll
        for (int ks = 0; ks < 8; ++ks) {
            half8 b0 = *(const half8*)&s_ph[( 0 + l15)*264 + ks*32 + quad*8];
            half8 b1 = *(const half8*)&s_ph[(16 + l15)*264 + ks*32 + quad*8];
            S0 = __builtin_amdgcn_mfma_f32_16x16x32_f16(t_hi[ks], b0, S0, 0,0,0);
            S1 = __builtin_amdgcn_mfma_f32_16x16x32_f16(t_hi[ks], b1, S1, 0,0,0);
        }

        // p = exp(clamp(S - shift, -85, 85)) -> bf16 into shared P
        unsigned short* pw = &s_p[wv][0];
        #pragma unroll
        for (int r = 0; r < 4; ++r) {
            float a0 = fminf(fmaxf(S0[r] - sh128[r], -85.f), 85.f);
            float a1 = fminf(fmaxf(S1[r] - sh128[r], -85.f), 85.f);
            pw[(quad*4 + r)*40 + l15]      = f2bf(__expf(a0));
            pw[(quad*4 + r)*40 + 16 + l15] = f2bf(__expf(a1));
        }
        asm volatile("s_waitcnt lgkmcnt(0)" ::: "memory");
        // own-row l accumulation (own s_p region; intra-wave wait only)
        short8 pown = *(const short8*)&s_p[wv][l15*40 + quad*8];
        accl = __builtin_amdgcn_mfma_f32_16x16x32_bf16(pown, ones, accl, 0,0,0);

        __syncthreads();                       // all waves' P visible

        // PV: O[all 64 q][this wave's 64 cols] += P @ g
        // g B-frags straight from global (L2-resident batch slice)
        short8 gf[4];
        #pragma unroll
        for (int ct = 0; ct < 4; ++ct)
            gf[ct] = *(const short8*)(gl + (size_t)ct*16*MM + key0);
        #pragma unroll
        for (int rt = 0; rt < 4; ++rt) {
            short8 pA = *(const short8*)&s_p[rt][l15*40 + quad*8];
            #pragma unroll
            for (int ct = 0; ct < 4; ++ct)
                O[rt][ct] = __builtin_amdgcn_mfma_f32_16x16x32_bf16(pA, gf[ct], O[rt][ct], 0,0,0);
        }
    }

    // broadcast row sums: wave wv owns l for queries wv*16..wv*16+15
    if (l15 == 0) {
        #pragma unroll
        for (int r = 0; r < 4; ++r) s_l[wv*16 + quad*4 + r] = accl[r];
    }
    __syncthreads();

    // epilogue: y = O/l, out = x + y  (wave wv writes cols wv*64..wv*64+63)
    #pragma unroll
    for (int rt = 0; rt < 4; ++rt) {
        #pragma unroll
        for (int r = 0; r < 4; ++r) {
            const int row = q0 + rt*16 + quad*4 + r;
            const float rl = 1.0f / s_l[rt*16 + quad*4 + r];
            #pragma unroll
            for (int ct = 0; ct < 4; ++ct) {
                const int c = wv*64 + ct*16 + l15;
                const size_t idx = (size_t)row*CC + c;
                out[idx] = x[idx] + O[rt][ct][r] * rl;
            }
        }
    }
}

// ---------------------------------------------------------------------------
extern "C" void kernel_launch(void* const* d_in, const int* in_sizes, int n_in,
                              void* d_out, int out_size, void* d_ws, size_t ws_size,
                              hipStream_t stream) {
    const float* x       = (const float*)d_in[0];
    const float* w_theta = (const float*)d_in[1];
    const float* w_phi   = (const float*)d_in[2];
    const float* w_g     = (const float*)d_in[3];
    float* out = (float*)d_out;

    // workspace (~34.4 MB; verified ws >= 56 MB in round 1)
    unsigned short* th    = (unsigned short*)d_ws;                 // fp16 16.78 MB
    unsigned short* ph    = th    + (size_t)NROWS*CC;              // fp16  8.39 MB
    unsigned short* g_t   = ph    + (size_t)PROWS*CC;              // bf16  8.39 MB
    unsigned short* wT_hi = g_t   + (size_t)PROWS*CC;              // bf16  0.39 MB
    unsigned short* wT_lo = wT_hi + (size_t)3*CC*CC;               // bf16  0.39 MB
    float*          phbar = (float*)(wT_lo + (size_t)3*CC*CC);     // fp32  8 KB

    hipMemsetAsync(phbar, 0, BB*CC*sizeof(float), stream);
    wsplit_kernel<<<dim3(4,4,3), 256, 0, stream>>>(w_theta, w_phi, w_g, wT_hi, wT_lo);
    proj_kernel<<<6144, 256, 0, stream>>>(x, wT_hi, wT_lo, th, ph, g_t);
    phimean_kernel<<<512, 256, 0, stream>>>(ph, phbar);
    attn_kernel<<<NROWS/64, 256, 0, stream>>>(x, th, ph, g_t, phbar, out);
}

// Round 6
// 285.125 us; speedup vs baseline: 1.4544x; 1.1006x over previous
//
#include <hip/hip_runtime.h>
#include <stdint.h>

// Problem constants (fixed by the reference): B=8, H=W=64, C=256
#define CC 256
#define NN 4096           // H*W
#define MM 2048           // NN/2 (pooled)
#define BB 8
#define NROWS (BB*NN)     // 32768 query rows
#define PROWS (BB*MM)     // 16384 pooled rows

typedef __attribute__((ext_vector_type(8))) short    short8;   // 8 bf16
typedef __attribute__((ext_vector_type(8))) _Float16 half8;    // 8 fp16
typedef __attribute__((ext_vector_type(4))) float    float4v;

__device__ __forceinline__ unsigned short f2bf(float f) {
    unsigned int u = __float_as_uint(f);
    u += 0x7fffu + ((u >> 16) & 1u);
    return (unsigned short)(u >> 16);
}
__device__ __forceinline__ float bf2f(unsigned short h) {
    return __uint_as_float(((unsigned int)h) << 16);
}
__device__ __forceinline__ unsigned short f2h(float f) {
    union { _Float16 h; unsigned short u; } cv; cv.h = (_Float16)f; return cv.u;
}
__device__ __forceinline__ float h2f(unsigned short u) {
    union { _Float16 h; unsigned short u; } cv; cv.u = u; return (float)cv.h;
}

// ---------------------------------------------------------------------------
// xsplit: x (fp32) -> x_hi/x_lo (bf16 split), elementwise, once.
// Removes the per-K-step VALU split from proj's hot loop (recomputed 12x).
// ---------------------------------------------------------------------------
__global__ __launch_bounds__(256) void xsplit_kernel(
    const float* __restrict__ x,
    unsigned short* __restrict__ x_hi,
    unsigned short* __restrict__ x_lo)
{
    const size_t i = ((size_t)blockIdx.x*256 + threadIdx.x) * 8;
    float4v a0 = *(const float4v*)(x + i);
    float4v a1 = *(const float4v*)(x + i + 4);
    short8 h, l;
    #pragma unroll
    for (int j = 0; j < 4; ++j) {
        unsigned short h0 = f2bf(a0[j]);
        h[j]   = (short)h0; l[j]   = (short)f2bf(a0[j] - bf2f(h0));
        unsigned short h1 = f2bf(a1[j]);
        h[4+j] = (short)h1; l[4+j] = (short)f2bf(a1[j] - bf2f(h1));
    }
    *(short8*)(x_hi + i) = h;
    *(short8*)(x_lo + i) = l;
}

// ---------------------------------------------------------------------------
// wsplit: transpose + bf16 hi/lo split the three 256x256 weights once.
// wT_hi/wT_lo layout: [widx][outcol][k]  (MFMA B-frags 16B contiguous)
// ---------------------------------------------------------------------------
__global__ void wsplit_kernel(const float* __restrict__ w_theta,
                              const float* __restrict__ w_phi,
                              const float* __restrict__ w_g,
                              unsigned short* __restrict__ wT_hi,
                              unsigned short* __restrict__ wT_lo)
{
    __shared__ float tile[64][65];
    const int widx = blockIdx.z;
    const int kt = blockIdx.x, ct = blockIdx.y;
    const float* w = (widx == 0) ? w_theta : (widx == 1) ? w_phi : w_g;
    const int t  = threadIdx.x;
    const int tc = t & 63, tr = t >> 6;
    #pragma unroll
    for (int i = 0; i < 16; ++i) {
        const int lk = tr*16 + i;
        tile[lk][tc] = w[(size_t)(kt*64 + lk)*CC + ct*64 + tc];
    }
    __syncthreads();
    #pragma unroll
    for (int i = 0; i < 16; ++i) {
        const int lc = tr*16 + i;
        float v = tile[tc][lc];
        const int c = ct*64 + lc, k = kt*64 + tc;
        unsigned short hh = f2bf(v);
        size_t o = ((size_t)widx*CC + c)*CC + k;
        wT_hi[o] = hh;
        wT_lo[o] = f2bf(v - bf2f(hh));
    }
}

// ---------------------------------------------------------------------------
// proj_kernel v6: one 64x64 slice of ONE projection per block. x comes
// PRE-SPLIT (x_hi/x_lo bf16) -> A-frags are pure 16B global loads (L2-local
// via rb%8 XCD swizzle); hot loop has near-zero VALU.
// theta/phi: 3-pass split-bf16; g: 1-pass.
// ---------------------------------------------------------------------------
__global__ __launch_bounds__(256, 4) void proj_kernel(
    const unsigned short* __restrict__ x_hi,
    const unsigned short* __restrict__ x_lo,
    const unsigned short* __restrict__ wT_hi,
    const unsigned short* __restrict__ wT_lo,
    unsigned short* __restrict__ th,
    unsigned short* __restrict__ ph,
    unsigned short* __restrict__ g_t)
{
    __shared__ unsigned short wt_hi[64*136];   // [64 cols][128 k + pad]
    __shared__ unsigned short wt_lo[64*136];

    const int tid  = threadIdx.x;
    const int rb   = blockIdx.x & 511;         // row-block (XCD = rb%8)
    const int cv   = blockIdx.x >> 9;          // 0..11 col-variant
    const int r0   = rb * 64;
    const int widx = cv >> 2;
    const int wc0  = (cv & 3) * 64;
    const unsigned short* wThp = wT_hi + ((size_t)widx*CC + wc0)*CC;
    const unsigned short* wTlp = wT_lo + ((size_t)widx*CC + wc0)*CC;
    const bool split3 = (widx < 2);            // theta/phi 3-pass; g 1-pass

    const int wv   = tid >> 6;
    const int lane = tid & 63;
    const int quad = lane >> 4;
    const int l15  = lane & 15;
    const int arow = r0 + wv*16 + l15;
    const unsigned short* axh = x_hi + (size_t)arow*CC + quad*8;
    const unsigned short* axl = x_lo + (size_t)arow*CC + quad*8;

    float4v acc[4];
    #pragma unroll
    for (int nf = 0; nf < 4; ++nf) acc[nf] = (float4v){0.f,0.f,0.f,0.f};

    for (int h = 0; h < 2; ++h) {
        __syncthreads();
        {   // stage pre-split W^T tile [64 cols][128 k] (pure copy)
            const int j    = tid & 63;
            const int kseg = tid >> 6;
            const size_t base = (size_t)j*CC + h*128 + kseg*32;
            const unsigned short* sh = wThp + base;
            unsigned short* dh = &wt_hi[j*136 + kseg*32];
            #pragma unroll
            for (int u = 0; u < 4; ++u)
                *(uint4*)(dh + u*8) = *(const uint4*)(sh + u*8);
            if (split3) {
                const unsigned short* sl = wTlp + base;
                unsigned short* dl = &wt_lo[j*136 + kseg*32];
                #pragma unroll
                for (int u = 0; u < 4; ++u)
                    *(uint4*)(dl + u*8) = *(const uint4*)(sl + u*8);
            }
        }
        __syncthreads();

        #pragma unroll
        for (int ks = 0; ks < 4; ++ks) {
            short8 a_hi = *(const short8*)(axh + h*128 + ks*32);
            short8 a_lo;
            if (split3) a_lo = *(const short8*)(axl + h*128 + ks*32);
            #pragma unroll
            for (int nf = 0; nf < 4; ++nf) {
                const int wrow = nf*16 + l15;
                short8 b_hi = *(const short8*)&wt_hi[wrow*136 + ks*32 + quad*8];
                acc[nf] = __builtin_amdgcn_mfma_f32_16x16x32_bf16(a_hi, b_hi, acc[nf], 0,0,0);
                if (split3) {
                    short8 b_lo = *(const short8*)&wt_lo[wrow*136 + ks*32 + quad*8];
                    acc[nf] = __builtin_amdgcn_mfma_f32_16x16x32_bf16(a_hi, b_lo, acc[nf], 0,0,0);
                    acc[nf] = __builtin_amdgcn_mfma_f32_16x16x32_bf16(a_lo, b_hi, acc[nf], 0,0,0);
                }
            }
        }
    }

    const int rowbase = r0 + wv*16 + quad*4;
    if (widx == 0) {                           // theta: unpooled, fp16 single
        #pragma unroll
        for (int nf = 0; nf < 4; ++nf) {
            const int c = wc0 + nf*16 + l15;
            #pragma unroll
            for (int r = 0; r < 4; ++r)
                th[(size_t)(rowbase + r)*CC + c] = f2h(acc[nf][r]);
        }
    } else if (widx == 1) {                    // phi: pool row pairs, fp16
        #pragma unroll
        for (int nf = 0; nf < 4; ++nf) {
            const int c = wc0 + nf*16 + l15;
            #pragma unroll
            for (int rp = 0; rp < 2; ++rp) {
                float v = fmaxf(acc[nf][2*rp], acc[nf][2*rp+1]);
                const int prow = rowbase/2 + rp;   // rowbase even -> exact
                ph[(size_t)prow*CC + c] = f2h(v);
            }
        }
    } else {                                   // g: pool, bf16, transposed
        #pragma unroll
        for (int nf = 0; nf < 4; ++nf) {
            const int c = wc0 + nf*16 + l15;
            #pragma unroll
            for (int rp = 0; rp < 2; ++rp) {
                float v = fmaxf(acc[nf][2*rp], acc[nf][2*rp+1]);
                const int prow = rowbase/2 + rp;
                const int b = prow >> 11;
                const int m = prow & 2047;
                g_t[((size_t)b*CC + c)*MM + m] = f2bf(v);
            }
        }
    }
}

// ---------------------------------------------------------------------------
// phimean: per-batch column mean of phi; 512 blocks (32 rows each).
// ---------------------------------------------------------------------------
__global__ void phimean_kernel(const unsigned short* __restrict__ ph,
                               float* __restrict__ phbar)
{
    const int b = blockIdx.x >> 6, chunk = blockIdx.x & 63;
    const int c = threadIdx.x;
    const size_t base = ((size_t)b*MM + chunk*32)*CC + c;
    float s = 0.f;
    for (int r = 0; r < 32; ++r) s += h2f(ph[base + (size_t)r*CC]);
    atomicAdd(&phbar[b*CC + c], s * (1.0f/MM));
}

// ---------------------------------------------------------------------------
// attn_kernel v6: v5 col-split + DOUBLE-BUFFERED phi staging.
//  - next tile's phi global loads issued at loop top (latency overlaps S);
//    LDS writes land before barrier 1; S reads alternate buffers.
//  - g B-frag global loads hoisted to loop top.
//  - shift softmax (theta.phibar + 128, clamp [-85,85]); ones-MFMA row sums.
// ---------------------------------------------------------------------------
__global__ __launch_bounds__(256, 3) void attn_kernel(
    const float* __restrict__ x,
    const unsigned short* __restrict__ th,
    const unsigned short* __restrict__ ph,
    const unsigned short* __restrict__ g_t,
    const float* __restrict__ phbar,
    float* __restrict__ out)
{
    __shared__ unsigned short s_ph[2][32*264]; // phi dbuf fp16, padded rows
    __shared__ unsigned short s_p[4][16*40];   // P: [src wave][16 q][32 k pad 40]
    __shared__ float          s_l[64];         // final row sums

    const int tid  = threadIdx.x;
    const int q0   = blockIdx.x * 64;
    const int b    = q0 >> 12;
    const int wv   = tid >> 6;
    const int lane = tid & 63;
    const int quad = lane >> 4;
    const int l15  = lane & 15;

    // staging geometry (same lanes for prologue and loop)
    const int sti = tid >> 3;                  // key row 0..31
    const int stc = (tid & 7) * 32;            // 32-channel segment
    const size_t phbase = (size_t)b * MM * CC;
    const unsigned short* stsrc = ph + phbase + (size_t)sti*CC + stc;

    // theta A-frags (fp16, single) for this wave's 16 rows
    half8 t_hi[8];
    {
        const unsigned short* bh = th + (size_t)(q0 + wv*16 + l15)*CC;
        #pragma unroll
        for (int ks = 0; ks < 8; ++ks)
            t_hi[ks] = *(const half8*)(bh + ks*32 + quad*8);
    }

    // per-row shift = theta . phibar (+128), moved to C-layout rows via shfl
    float sh128[4];
    {
        float sp = 0.f;
        #pragma unroll
        for (int ks = 0; ks < 8; ++ks) {
            const int k0 = ks*32 + quad*8;
            float4v m0 = *(const float4v*)&phbar[b*CC + k0];
            float4v m1 = *(const float4v*)&phbar[b*CC + k0 + 4];
            #pragma unroll
            for (int j = 0; j < 4; ++j) {
                sp += (float)t_hi[ks][j]   * m0[j];
                sp += (float)t_hi[ks][4+j] * m1[j];
            }
        }
        sp += __shfl_xor(sp, 16);
        sp += __shfl_xor(sp, 32);
        #pragma unroll
        for (int r = 0; r < 4; ++r)
            sh128[r] = __shfl(sp, quad*4 + r) + 128.f;
    }

    // O: all 64 block-queries x this wave's 64-col strip
    float4v O[4][4];
    #pragma unroll
    for (int rt = 0; rt < 4; ++rt)
        #pragma unroll
        for (int ct = 0; ct < 4; ++ct) O[rt][ct] = (float4v){0.f,0.f,0.f,0.f};
    float4v accl = (float4v){0.f,0.f,0.f,0.f};

    short8 ones;
    #pragma unroll
    for (int j = 0; j < 8; ++j) ones[j] = (short)0x3F80;   // bf16 1.0

    // this wave's g strip base: cols wv*64.., lane row l15, k-offset quad*8
    const unsigned short* gl =
        g_t + ((size_t)b*CC + wv*64 + l15)*MM + quad*8;

    // prologue: stage tile 0 into buf 0
    {
        unsigned short* dh = &s_ph[0][sti*264 + stc];
        #pragma unroll
        for (int u = 0; u < 4; ++u)
            *(uint4*)(dh + u*8) = *(const uint4*)(stsrc + u*8);
    }
    __syncthreads();

    for (int kt = 0; kt < 64; ++kt) {
        const int key0 = kt * 32;
        const int cur  = kt & 1;

        // issue next-tile phi loads early (latency hides under S-MFMA)
        uint4 stg[4];
        if (kt < 63) {
            const unsigned short* sn = stsrc + (size_t)(key0 + 32)*CC;
            #pragma unroll
            for (int u = 0; u < 4; ++u) stg[u] = *(const uint4*)(sn + u*8);
        }
        // issue this tile's g loads early too
        short8 gf[4];
        #pragma unroll
        for (int ct = 0; ct < 4; ++ct)
            gf[ct] = *(const short8*)(gl + (size_t)ct*16*MM + key0);

        // S = theta @ phi^T, 1-pass fp16, from current buffer
        float4v S0 = (float4v){0.f,0.f,0.f,0.f};
        float4v S1 = (float4v){0.f,0.f,0.f,0.f};
        #pragma unroll
        for (int ks = 0; ks < 8; ++ks) {
            half8 b0 = *(const half8*)&s_ph[cur][( 0 + l15)*264 + ks*32 + quad*8];
            half8 b1 = *(const half8*)&s_ph[cur][(16 + l15)*264 + ks*32 + quad*8];
            S0 = __builtin_amdgcn_mfma_f32_16x16x32_f16(t_hi[ks], b0, S0, 0,0,0);
            S1 = __builtin_amdgcn_mfma_f32_16x16x32_f16(t_hi[ks], b1, S1, 0,0,0);
        }

        // p = exp(clamp(S - shift, -85, 85)) -> bf16 into shared P
        unsigned short* pw = &s_p[wv][0];
        #pragma unroll
        for (int r = 0; r < 4; ++r) {
            float a0 = fminf(fmaxf(S0[r] - sh128[r], -85.f), 85.f);
            float a1 = fminf(fmaxf(S1[r] - sh128[r], -85.f), 85.f);
            pw[(quad*4 + r)*40 + l15]      = f2bf(__expf(a0));
            pw[(quad*4 + r)*40 + 16 + l15] = f2bf(__expf(a1));
        }
        asm volatile("s_waitcnt lgkmcnt(0)" ::: "memory");
        // own-row l accumulation (own s_p region; intra-wave wait only)
        short8 pown = *(const short8*)&s_p[wv][l15*40 + quad*8];
        accl = __builtin_amdgcn_mfma_f32_16x16x32_bf16(pown, ones, accl, 0,0,0);

        // write staged phi into the other buffer before the barrier
        if (kt < 63) {
            unsigned short* dh = &s_ph[cur ^ 1][sti*264 + stc];
            #pragma unroll
            for (int u = 0; u < 4; ++u) *(uint4*)(dh + u*8) = stg[u];
        }
        __syncthreads();                       // P visible; next phi staged

        // PV: O[all 64 q][this wave's 64 cols] += P @ g
        #pragma unroll
        for (int rt = 0; rt < 4; ++rt) {
            short8 pA = *(const short8*)&s_p[rt][l15*40 + quad*8];
            #pragma unroll
            for (int ct = 0; ct < 4; ++ct)
                O[rt][ct] = __builtin_amdgcn_mfma_f32_16x16x32_bf16(pA, gf[ct], O[rt][ct], 0,0,0);
        }
        __syncthreads();                       // s_p reusable next iter
    }

    // broadcast row sums: wave wv owns l for queries wv*16..wv*16+15
    if (l15 == 0) {
        #pragma unroll
        for (int r = 0; r < 4; ++r) s_l[wv*16 + quad*4 + r] = accl[r];
    }
    __syncthreads();

    // epilogue: y = O/l, out = x + y  (wave wv writes cols wv*64..wv*64+63)
    #pragma unroll
    for (int rt = 0; rt < 4; ++rt) {
        #pragma unroll
        for (int r = 0; r < 4; ++r) {
            const int row = q0 + rt*16 + quad*4 + r;
            const float rl = 1.0f / s_l[rt*16 + quad*4 + r];
            #pragma unroll
            for (int ct = 0; ct < 4; ++ct) {
                const int c = wv*64 + ct*16 + l15;
                const size_t idx = (size_t)row*CC + c;
                out[idx] = x[idx] + O[rt][ct][r] * rl;
            }
        }
    }
}

// ---------------------------------------------------------------------------
extern "C" void kernel_launch(void* const* d_in, const int* in_sizes, int n_in,
                              void* d_out, int out_size, void* d_ws, size_t ws_size,
                              hipStream_t stream) {
    const float* x       = (const float*)d_in[0];
    const float* w_theta = (const float*)d_in[1];
    const float* w_phi   = (const float*)d_in[2];
    const float* w_g     = (const float*)d_in[3];
    float* out = (float*)d_out;

    // workspace (~51.2 MB; verified ws >= 56 MB in round 1)
    unsigned short* th    = (unsigned short*)d_ws;                 // fp16 16.78 MB
    unsigned short* ph    = th    + (size_t)NROWS*CC;              // fp16  8.39 MB
    unsigned short* g_t   = ph    + (size_t)PROWS*CC;              // bf16  8.39 MB
    unsigned short* x_hi  = g_t   + (size_t)PROWS*CC;              // bf16  8.39 MB
    unsigned short* x_lo  = x_hi  + (size_t)NROWS*CC;              // bf16  8.39 MB
    unsigned short* wT_hi = x_lo  + (size_t)NROWS*CC;              // bf16  0.39 MB
    unsigned short* wT_lo = wT_hi + (size_t)3*CC*CC;               // bf16  0.39 MB
    float*          phbar = (float*)(wT_lo + (size_t)3*CC*CC);     // fp32  8 KB

    hipMemsetAsync(phbar, 0, BB*CC*sizeof(float), stream);
    xsplit_kernel<<<NROWS*CC/8/256, 256, 0, stream>>>(x, x_hi, x_lo);
    wsplit_kernel<<<dim3(4,4,3), 256, 0, stream>>>(w_theta, w_phi, w_g, wT_hi, wT_lo);
    proj_kernel<<<6144, 256, 0, stream>>>(x_hi, x_lo, wT_hi, wT_lo, th, ph, g_t);
    phimean_kernel<<<512, 256, 0, stream>>>(ph, phbar);
    attn_kernel<<<NROWS/64, 256, 0, stream>>>(x, th, ph, g_t, phbar, out);
}